// Round 2
// baseline (1921.051 us; speedup 1.0000x reference)
//
#include <hip/hip_runtime.h>
#include <hip/hip_bf16.h>

// CrossExpertRefinement on MI355X — round 2: bf16x3 split-GEMM on MFMA.
// All GEMM stages C = A @ W^T computed as (A_hi+A_lo)(W_hi+W_lo) dropping
// lo*lo: 3 bf16 MFMAs per product, fp32 accumulate. Error ~1e-5 absolute.
// Pipeline:
//   K1  x_e @ Win_e^T            -> S (65536,512)   [token-major, ld 2048]
//   K2  per-row LN stats (mu, rstd) of S
//   per chunk of 2048 tokens:
//     K3  LN(S) @ Wqkv^T + bqkv  -> QKVc   (LN fused into A staging)
//     K4a exact fp32 4x4 masked attention -> CTXc
//     K4b CTXc @ Wo^T + bo + S   -> S (in-place residual accumulate)
//   K5  S_e @ Wout_e^T + x_e     -> out
// ws: S[65536*512] mu[65536] rstd[65536] QKVc[8192*1536] CTXc[8192*512] ~202MB

#define BM 128
#define BN 128
#define BK 32

using bf16x4 = __attribute__((ext_vector_type(4))) __bf16;
using bf16x8 = __attribute__((ext_vector_type(8))) __bf16;
using f32x16 = __attribute__((ext_vector_type(16))) float;

// Stage one 32-k slice of a row into LDS as hi|lo bf16 with XOR swizzle.
// LDS row layout: 128 bytes = hi bf16 k0..k31 (64B) | lo bf16 k0..k31 (64B),
// each 8B-group's byte offset XORed with (row&7)<<4 (bijective, bank-spread).
template <bool LN>
__device__ __forceinline__ void stage_row(
    const float* __restrict__ row, __bf16* __restrict__ lds,
    int srow, int koff, int k0, int K, float amu, float ars,
    const float* __restrict__ lng, const float* __restrict__ lnb)
{
    char* base = (char*)lds + srow * 128;
    const int sw = (srow & 7) << 4;
#pragma unroll
    for (int i = 0; i < 4; ++i) {
        const int kk = koff + i * 4;
        const int gk = k0 + kk;
        float4 v = make_float4(0.f, 0.f, 0.f, 0.f);
        if (row) {
            if (gk + 3 < K) {
                v = *(const float4*)(row + gk);
            } else {
                if (gk + 0 < K) v.x = row[gk + 0];
                if (gk + 1 < K) v.y = row[gk + 1];
                if (gk + 2 < K) v.z = row[gk + 2];
            }
        }
        if (LN) {  // only used with K=512 (never OOB)
            v.x = (v.x - amu) * ars * lng[gk + 0] + lnb[gk + 0];
            v.y = (v.y - amu) * ars * lng[gk + 1] + lnb[gk + 1];
            v.z = (v.z - amu) * ars * lng[gk + 2] + lnb[gk + 2];
            v.w = (v.w - amu) * ars * lng[gk + 3] + lnb[gk + 3];
        }
        bf16x4 h4, l4;
        {
            __bf16 h;
            h = (__bf16)v.x; h4[0] = h; l4[0] = (__bf16)(v.x - (float)h);
            h = (__bf16)v.y; h4[1] = h; l4[1] = (__bf16)(v.y - (float)h);
            h = (__bf16)v.z; h4[2] = h; l4[2] = (__bf16)(v.z - (float)h);
            h = (__bf16)v.w; h4[3] = h; l4[3] = (__bf16)(v.w - (float)h);
        }
        const int q = (koff >> 2) + i;               // 0..7 (8B group in row)
        *(bf16x4*)(base + ((8 * q) ^ sw)) = h4;      // hi half
        *(bf16x4*)(base + ((64 + 8 * q) ^ sw)) = l4; // lo half
    }
}

__global__ __launch_bounds__(256, 2) void gemm_bf16x3(
    const float* __restrict__ A, int lda,
    const float* __restrict__ B, int ldb,   // torch Linear layout: N x K
    float* __restrict__ C, int ldc,
    const float* __restrict__ bias,
    const float* __restrict__ resid, int ldr,
    const float* __restrict__ muP, const float* __restrict__ rsP,
    const float* __restrict__ lng, const float* __restrict__ lnb,
    int M, int N, int K, int accC)
{
    __shared__ __align__(16) __bf16 lA[128 * 64];  // 128 rows x 128B swizzled
    __shared__ __align__(16) __bf16 lB[128 * 64];

    const int tid = threadIdx.x;
    const int m0 = blockIdx.x * BM;
    const int n0 = blockIdx.y * BN;

    // staging coords: 2 threads per tile row, each covers 16 consecutive k
    const int srow = tid >> 1;
    const int koff = (tid & 1) * 16;
    const int gr = m0 + srow;                 // M is always a multiple of 128
    const int gn = n0 + srow;
    float amu = 0.f, ars = 1.f;
    if (muP) { amu = muP[gr]; ars = rsP[gr]; }
    const float* __restrict__ Arow = A + (size_t)gr * lda;
    const float* __restrict__ Brow = (gn < N) ? (B + (size_t)gn * ldb) : nullptr;

    // fragment coords: wave (wr,wc) owns a 64x64 quadrant = 2x2 of 32x32
    const int w = tid >> 6, lane = tid & 63;
    const int wr = w >> 1, wc = w & 1;
    const int lrow = lane & 31;               // row/col within 32-fragment
    const int lkg = lane >> 5;                // k half-group (0/1)
    const int swz = (lane & 7) << 4;          // read-side XOR (row&7 == lane&7)

    f32x16 acc[2][2];
#pragma unroll
    for (int a = 0; a < 2; ++a)
#pragma unroll
        for (int b = 0; b < 2; ++b)
#pragma unroll
            for (int r = 0; r < 16; ++r) acc[a][b][r] = 0.f;

    for (int k0 = 0; k0 < K; k0 += BK) {
        if (muP) stage_row<true >(Arow, lA, srow, koff, k0, K, amu, ars, lng, lnb);
        else     stage_row<false>(Arow, lA, srow, koff, k0, K, 0.f, 0.f, nullptr, nullptr);
        stage_row<false>(Brow, lB, srow, koff, k0, K, 0.f, 0.f, nullptr, nullptr);
        __syncthreads();

        bf16x8 ah[2][2], al[2][2], bh[2][2], bl[2][2];  // [frag][kgroup]
#pragma unroll
        for (int f = 0; f < 2; ++f) {
            const char* baA = (const char*)lA + (wr * 64 + f * 32 + lrow) * 128;
            const char* baB = (const char*)lB + (wc * 64 + f * 32 + lrow) * 128;
#pragma unroll
            for (int g = 0; g < 2; ++g) {
                const int off = g * 32 + lkg * 16;     // 16B slot for k=(g*16+lkg*8)..+7
                ah[f][g] = *(const bf16x8*)(baA + ((off) ^ swz));
                al[f][g] = *(const bf16x8*)(baA + ((64 + off) ^ swz));
                bh[f][g] = *(const bf16x8*)(baB + ((off) ^ swz));
                bl[f][g] = *(const bf16x8*)(baB + ((64 + off) ^ swz));
            }
        }
#pragma unroll
        for (int g = 0; g < 2; ++g)
#pragma unroll
            for (int fm = 0; fm < 2; ++fm)
#pragma unroll
                for (int fn = 0; fn < 2; ++fn) {
                    acc[fm][fn] = __builtin_amdgcn_mfma_f32_32x32x16_bf16(
                        ah[fm][g], bh[fn][g], acc[fm][fn], 0, 0, 0);
                    acc[fm][fn] = __builtin_amdgcn_mfma_f32_32x32x16_bf16(
                        ah[fm][g], bl[fn][g], acc[fm][fn], 0, 0, 0);
                    acc[fm][fn] = __builtin_amdgcn_mfma_f32_32x32x16_bf16(
                        al[fm][g], bh[fn][g], acc[fm][fn], 0, 0, 0);
                }
        __syncthreads();
    }

    // Epilogue. C/D map (m74/m101): col=lane&31, row=(r&3)+8*(r>>2)+4*(lane>>5)
#pragma unroll
    for (int fm = 0; fm < 2; ++fm)
#pragma unroll
        for (int fn = 0; fn < 2; ++fn) {
            const int gc = n0 + wc * 64 + fn * 32 + lrow;
            if (gc < N) {
                const float bia = bias ? bias[gc] : 0.f;
#pragma unroll
                for (int r = 0; r < 16; ++r) {
                    const int gm = m0 + wr * 64 + fm * 32 + (r & 3) + 8 * (r >> 2) + 4 * lkg;
                    float v = acc[fm][fn][r] + bia;
                    if (resid) v += resid[(size_t)gm * ldr + gc];
                    const size_t ci = (size_t)gm * ldc + gc;
                    if (accC) v += C[ci];
                    C[ci] = v;
                }
            }
        }
}

__global__ __launch_bounds__(256) void ln_stats(
    const float* __restrict__ S, float* __restrict__ mu, float* __restrict__ rstd)
{
    const int row = blockIdx.x * 4 + (threadIdx.x >> 6);
    const int lane = threadIdx.x & 63;
    const float4* p = (const float4*)(S + (size_t)row * 512);
    const float4 a = p[lane];
    const float4 b = p[64 + lane];
    float s = a.x + a.y + a.z + a.w + b.x + b.y + b.z + b.w;
    float q = a.x * a.x + a.y * a.y + a.z * a.z + a.w * a.w +
              b.x * b.x + b.y * b.y + b.z * b.z + b.w * b.w;
#pragma unroll
    for (int o = 32; o > 0; o >>= 1) {
        s += __shfl_xor(s, o);
        q += __shfl_xor(q, o);
    }
    if (lane == 0) {
        const float m = s * (1.f / 512.f);
        const float var = q * (1.f / 512.f) - m * m;  // population var (jnp.var)
        mu[row] = m;
        rstd[row] = rsqrtf(var + 1e-5f);
    }
}

// One wave per token. 4x4 DAG-masked (lower-tri) MHA over experts, 8 heads of 64.
// Row 0's softmax is a singleton -> ctx0 = v0 exactly; q0 never needed.
__global__ __launch_bounds__(256) void attn_refine(
    const float* __restrict__ QKV, float* __restrict__ CTX, int ntok)
{
    const int w = threadIdx.x >> 6;
    const int lane = threadIdx.x & 63;
    const int t = blockIdx.x * 4 + w;
    if (t >= ntok) return;
    const float* __restrict__ base = QKV + (size_t)t * 4 * 1536;
    float* __restrict__ cb = CTX + (size_t)t * 4 * 512;
#pragma unroll
    for (int h = 0; h < 8; ++h) {
        const int off = h * 64 + lane;
        const float q1 = base[1536 + off];
        const float q2 = base[2 * 1536 + off];
        const float q3 = base[3 * 1536 + off];
        const float k0 = base[512 + off];
        const float k1 = base[1536 + 512 + off];
        const float k2 = base[2 * 1536 + 512 + off];
        const float k3 = base[3 * 1536 + 512 + off];
        const float v0 = base[1024 + off];
        const float v1 = base[1536 + 1024 + off];
        const float v2 = base[2 * 1536 + 1024 + off];
        const float v3 = base[3 * 1536 + 1024 + off];
        float s10 = q1 * k0, s11 = q1 * k1;
        float s20 = q2 * k0, s21 = q2 * k1, s22 = q2 * k2;
        float s30 = q3 * k0, s31 = q3 * k1, s32 = q3 * k2, s33 = q3 * k3;
#pragma unroll
        for (int o = 32; o > 0; o >>= 1) {
            s10 += __shfl_xor(s10, o); s11 += __shfl_xor(s11, o);
            s20 += __shfl_xor(s20, o); s21 += __shfl_xor(s21, o); s22 += __shfl_xor(s22, o);
            s30 += __shfl_xor(s30, o); s31 += __shfl_xor(s31, o);
            s32 += __shfl_xor(s32, o); s33 += __shfl_xor(s33, o);
        }
        const float sc = 0.125f;  // 1/sqrt(64)
        s10 *= sc; s11 *= sc;
        s20 *= sc; s21 *= sc; s22 *= sc;
        s30 *= sc; s31 *= sc; s32 *= sc; s33 *= sc;

        const float m1 = fmaxf(s10, s11);
        const float e10 = expf(s10 - m1), e11 = expf(s11 - m1);
        const float r1 = 1.f / (e10 + e11);
        const float m2 = fmaxf(fmaxf(s20, s21), s22);
        const float e20 = expf(s20 - m2), e21 = expf(s21 - m2), e22 = expf(s22 - m2);
        const float r2 = 1.f / (e20 + e21 + e22);
        const float m3 = fmaxf(fmaxf(s30, s31), fmaxf(s32, s33));
        const float e30 = expf(s30 - m3), e31 = expf(s31 - m3);
        const float e32 = expf(s32 - m3), e33 = expf(s33 - m3);
        const float r3 = 1.f / (e30 + e31 + e32 + e33);

        cb[off] = v0;
        cb[512 + off]  = (e10 * v0 + e11 * v1) * r1;
        cb[1024 + off] = (e20 * v0 + e21 * v1 + e22 * v2) * r2;
        cb[1536 + off] = (e30 * v0 + e31 * v1 + e32 * v2 + e33 * v3) * r3;
    }
}

extern "C" void kernel_launch(void* const* d_in, const int* in_sizes, int n_in,
                              void* d_out, int out_size, void* d_ws, size_t ws_size,
                              hipStream_t stream)
{
    // setup_inputs() dict order: x0,Win0,Wout0, x1,Win1,Wout1, x2,Win2,Wout2,
    //                            x3,Win3,Wout3, ln_g,ln_b, Wqkv,bqkv, Wo,bo
    const float* x[4]    = {(const float*)d_in[0], (const float*)d_in[3],
                            (const float*)d_in[6], (const float*)d_in[9]};
    const float* Win[4]  = {(const float*)d_in[1], (const float*)d_in[4],
                            (const float*)d_in[7], (const float*)d_in[10]};
    const float* Wout[4] = {(const float*)d_in[2], (const float*)d_in[5],
                            (const float*)d_in[8], (const float*)d_in[11]};
    const float* ln_g = (const float*)d_in[12];
    const float* ln_b = (const float*)d_in[13];
    const float* Wqkv = (const float*)d_in[14];
    const float* bqkv = (const float*)d_in[15];
    const float* Wo   = (const float*)d_in[16];
    const float* bo   = (const float*)d_in[17];
    float* out = (float*)d_out;

    const int dE[4] = {128, 128, 1006, 104};
    const int NTOK = 8 * 2048;   // 16384 tokens
    const int ROWS = NTOK * 4;   // 65536 token-expert rows

    float* S    = (float*)d_ws;                       // 65536*512
    float* muB  = S + (size_t)ROWS * 512;             // 65536
    float* rsB  = muB + ROWS;                         // 65536
    float* QKVc = rsB + ROWS;                         // 8192*1536
    float* CTXc = QKVc + (size_t)8192 * 1536;         // 8192*512

    // K1: per-expert input projections -> S (row stride 2048, col offset e*512)
    for (int e = 0; e < 4; ++e) {
        gemm_bf16x3<<<dim3(NTOK / BM, 512 / BN), 256, 0, stream>>>(
            x[e], dE[e], Win[e], dE[e], S + e * 512, 2048,
            nullptr, nullptr, 0, nullptr, nullptr, nullptr, nullptr,
            NTOK, 512, dE[e], 0);
    }

    // K2: LayerNorm statistics per (token,expert) row of S
    ln_stats<<<ROWS / 4, 256, 0, stream>>>(S, muB, rsB);

    // Chunked QKV -> attention -> Wo(+residual into S)
    const int NCH = 8;
    const int TPC = NTOK / NCH;   // 2048 tokens / chunk
    const int RPC = TPC * 4;      // 8192 rows / chunk
    for (int c = 0; c < NCH; ++c) {
        const size_t rb = (size_t)c * RPC;
        // K3: qkv = LN(S) @ Wqkv^T + bqkv (LN fused on A staging)
        gemm_bf16x3<<<dim3(RPC / BM, 1536 / BN), 256, 0, stream>>>(
            S + rb * 512, 512, Wqkv, 512, QKVc, 1536,
            bqkv, nullptr, 0, muB + rb, rsB + rb, ln_g, ln_b,
            RPC, 1536, 512, 0);
        // K4a: exact fp32 masked 4x4 attention per token
        attn_refine<<<TPC / 4, 256, 0, stream>>>(QKVc, CTXc, TPC);
        // K4b: S += ctx @ Wo^T + bo (in-place accumulate)
        gemm_bf16x3<<<dim3(RPC / BM, 512 / BN), 256, 0, stream>>>(
            CTXc, 512, Wo, 512, S + rb * 512, 512,
            bo, nullptr, 0, nullptr, nullptr, nullptr, nullptr,
            RPC, 512, 512, 1);
    }

    // K5: per-expert output projections + input residual -> out
    size_t off = 0;
    for (int e = 0; e < 4; ++e) {
        gemm_bf16x3<<<dim3(NTOK / BM, (dE[e] + BN - 1) / BN), 256, 0, stream>>>(
            S + e * 512, 2048, Wout[e], 512, out + off, dE[e],
            nullptr, x[e], dE[e], nullptr, nullptr, nullptr, nullptr,
            NTOK, dE[e], 512, 0);
        off += (size_t)NTOK * dE[e];
    }
}